// Round 3
// baseline (267.139 us; speedup 1.0000x reference)
//
#include <hip/hip_runtime.h>

// SimpleEncoder: LSTM(B=4096, S=512, I=3, H=16) + Linear(16->5) + clip(+-10)
//
// R3: 32 lanes per batch element -> 2048 waves -> 2 waves/SIMD (R2 was pinned
// at 1 wave/SIMD, 845 cyc/step with ~400 stall cycles exposed).
// Per 32-lane group: lanes 0-15 (row A) own gate pair {i,f} of unit j, lanes
// 16-31 (row B) own {g,o}, packed as f32x2 -> v_pk_fma_f32. After activations
// one ds_swizzle xor16 pair exchanges gate values and BOTH rows compute the
// identical c/h update, so h_j is present in both rows and the per-row DPP
// row_newbcast needs no replicate step. Signs/log2e folded into weights so
// the activation is uniform across rows: r = rcp(1+exp2(z)).

#define TS 512
#define LOG2E 1.44269504088896340736f

typedef float f32x2 __attribute__((ext_vector_type(2)));

// DPP row_newbcast:K — broadcast lane K of each 16-lane row to the whole row.
#define BCAST(K) hbr[K] = __int_as_float( \
    __builtin_amdgcn_update_dpp(0, hvi, 0x150 + (K), 0xf, 0xf, true))
#define BCAST_ALL() \
  BCAST(0); BCAST(1); BCAST(2); BCAST(3); BCAST(4); BCAST(5); BCAST(6); BCAST(7); \
  BCAST(8); BCAST(9); BCAST(10); BCAST(11); BCAST(12); BCAST(13); BCAST(14); BCAST(15)

// ds_swizzle BitMode xor16: lane l <-> lane l^16 within each 32-lane group.
#define SWZ16(vi) __builtin_amdgcn_ds_swizzle((vi), 0x401F)

__global__ __launch_bounds__(256, 2)
void lstm_enc_kernel(const float* __restrict__ x,
                     const float* __restrict__ W_ih,
                     const float* __restrict__ W_hh,
                     const float* __restrict__ b_ih,
                     const float* __restrict__ b_hh,
                     const float* __restrict__ W_lin,
                     const float* __restrict__ b_lin,
                     float* __restrict__ out) {
  const int tid = threadIdx.x;
  const int j = tid & 15;                        // hidden unit owned by this lane
  const bool rowB = (tid & 16) != 0;             // row A: {i,f}; row B: {g,o}
  const int batch = blockIdx.x * 8 + (tid >> 5); // 32 lanes per batch
  const int jo = (j < 5) ? j : 0;                // clamped row for W_lin loads

  // gate rows + activation scale folding:
  //  i,f,o: z = -log2e * preact  -> sigmoid = rcp(1+exp2(z))
  //  g:     z = +2log2e * preact -> sg = rcp(1+exp2(z)), tanh = 1-2*sg
  const int g0 = rowB ? j + 32 : j;              // g : i
  const int g1 = rowB ? j + 48 : j + 16;         // o : f
  const float s0 = rowB ? 2.0f * LOG2E : -LOG2E;
  const float s1 = -LOG2E;

  f32x2 wz[16];                                  // packed W_hh for this lane's 2 gates
  float wl[16];
#pragma unroll
  for (int k = 0; k < 16; ++k) {
    wz[k] = f32x2{W_hh[g0 * 16 + k] * s0, W_hh[g1 * 16 + k] * s1};
    wl[k] = W_lin[jo * 16 + k];
  }
  f32x2 xw[3];
#pragma unroll
  for (int i = 0; i < 3; ++i) {
    xw[i] = f32x2{W_ih[g0 * 3 + i] * s0, W_ih[g1 * 3 + i] * s1};
  }
  const f32x2 bz = f32x2{(b_ih[g0] + b_hh[g0]) * s0,
                         (b_ih[g1] + b_hh[g1]) * s1};
  const float bl = b_lin[jo];

  const float* __restrict__ xb = x + (size_t)batch * (TS * 3);
  float* __restrict__ ob = out + (size_t)batch * (TS * 5) + j;
  const bool storer = (tid & 31) < 5;            // row A lanes 0..4 store

  float h = 0.0f, c = 0.0f;
  float x0 = xb[0], x1 = xb[1], x2 = xb[2];

  for (int t = 0; t < TS; ++t) {
    // prefetch next timestep's input ((t+1)&511 wraps in-bounds at the end)
    const int tn = (t + 1) & (TS - 1);
    const float nx0 = xb[tn * 3 + 0];
    const float nx1 = xb[tn * 3 + 1];
    const float nx2 = xb[tn * 3 + 2];

    // broadcast h_{t-1}: both rows hold identical h_j, DPP within each row
    float hbr[16];
    const int hvi = __float_as_int(h);
    BCAST_ALL();

    // gate pre-activations, two independent pk_fma chains (even/odd k)
    f32x2 za = bz, zb = f32x2{0.0f, 0.0f};
    za = f32x2{x0, x0} * xw[0] + za;
    zb = f32x2{x1, x1} * xw[1] + zb;
    za = f32x2{x2, x2} * xw[2] + za;
#pragma unroll
    for (int k = 0; k < 16; k += 2) {
      za = f32x2{hbr[k], hbr[k]} * wz[k] + za;
      zb = f32x2{hbr[k + 1], hbr[k + 1]} * wz[k + 1] + zb;
    }
    const f32x2 z = za + zb;

    // output projection W_lin . h_{t-1} (row A lanes' result is stored)
    float oa = bl;
#pragma unroll
    for (int k = 0; k < 16; ++k) oa = fmaf(hbr[k], wl[k], oa);
    if (t > 0 && storer) {
      ob[(t - 1) * 5] = fminf(fmaxf(oa, -10.0f), 10.0f);
    }

    // uniform activation: r = rcp(1 + exp2(z))
    const float r0 = __builtin_amdgcn_rcpf(1.0f + __builtin_amdgcn_exp2f(z.x));
    const float r1 = __builtin_amdgcn_rcpf(1.0f + __builtin_amdgcn_exp2f(z.y));

    // exchange across rows: row A has {ig,fg}=r0,r1; row B has {sg,og}=r0,r1
    const float q0 = __int_as_float(SWZ16(__float_as_int(r0)));
    const float q1 = __int_as_float(SWZ16(__float_as_int(r1)));
    const float ig = rowB ? q0 : r0;
    const float fg = rowB ? q1 : r1;
    const float sg = rowB ? r0 : q0;
    const float og = rowB ? r1 : q1;

    // both rows compute the identical c,h update (keeps h in all 32 lanes)
    const float gg = fmaf(-2.0f, sg, 1.0f);      // tanh(g)
    c = fmaf(fg, c, ig * gg);
    const float tc = fmaf(-2.0f,
        __builtin_amdgcn_rcpf(1.0f + __builtin_amdgcn_exp2f((2.0f * LOG2E) * c)), 1.0f);
    h = og * tc;

    x0 = nx0; x1 = nx1; x2 = nx2;
  }

  // final timestep's output (uses h_{S-1})
  {
    float hbr[16];
    const int hvi = __float_as_int(h);
    BCAST_ALL();
    float oa = bl;
#pragma unroll
    for (int k = 0; k < 16; ++k) oa = fmaf(hbr[k], wl[k], oa);
    if (storer) {
      ob[(TS - 1) * 5] = fminf(fmaxf(oa, -10.0f), 10.0f);
    }
  }
}

extern "C" void kernel_launch(void* const* d_in, const int* in_sizes, int n_in,
                              void* d_out, int out_size, void* d_ws, size_t ws_size,
                              hipStream_t stream) {
  const float* x     = (const float*)d_in[0];
  const float* W_ih  = (const float*)d_in[1];
  const float* W_hh  = (const float*)d_in[2];
  const float* b_ih  = (const float*)d_in[3];
  const float* b_hh  = (const float*)d_in[4];
  const float* W_lin = (const float*)d_in[5];
  const float* b_lin = (const float*)d_in[6];
  float* out = (float*)d_out;

  const int B = in_sizes[0] / (TS * 3);   // 4096
  const int grid = B / 8;                 // 8 batch elements per 256-thread block
  lstm_enc_kernel<<<grid, 256, 0, stream>>>(x, W_ih, W_hh, b_ih, b_hh, W_lin, b_lin, out);
}

// Round 4
// 220.145 us; speedup vs baseline: 1.2135x; 1.2135x over previous
//
#include <hip/hip_runtime.h>

// SimpleEncoder: LSTM(B=4096, S=512, I=3, H=16) + Linear(16->5) + clip(+-10)
//
// R4: R2 layout (16 lanes/batch, lane j owns unit j, gate rows j/j+16/j+32/j+48,
// DPP row_newbcast h-broadcast, pk_fma gate pairs) + LDS staging of x:
//  - x staged in 64-step chunks, double-buffered, ENTIRELY INTRA-WAVE (each
//    16-lane group loads/reads only its own batch) -> zero barriers.
//  - global loads for chunk ch+2 issued mid-chunk (~64-step prefetch distance);
//    per-step x comes from one ds_read_b128 prefetched 2 steps ahead.
//  - only global op left in the loop is the fire-and-forget output store.

#define TS 512
#define LOG2E 1.44269504088896340736f

typedef float f32x2 __attribute__((ext_vector_type(2)));

// DPP row_newbcast:K — broadcast lane K of each 16-lane row to the whole row.
#define BCAST(K) hbr[K] = __int_as_float( \
    __builtin_amdgcn_update_dpp(0, hvi, 0x150 + (K), 0xf, 0xf, true))
#define BCAST_ALL() \
  BCAST(0); BCAST(1); BCAST(2); BCAST(3); BCAST(4); BCAST(5); BCAST(6); BCAST(7); \
  BCAST(8); BCAST(9); BCAST(10); BCAST(11); BCAST(12); BCAST(13); BCAST(14); BCAST(15)

__global__ __launch_bounds__(256, 1)
void lstm_enc_kernel(const float* __restrict__ x,
                     const float* __restrict__ W_ih,
                     const float* __restrict__ W_hh,
                     const float* __restrict__ b_ih,
                     const float* __restrict__ b_hh,
                     const float* __restrict__ W_lin,
                     const float* __restrict__ b_lin,
                     float* __restrict__ out) {
  const int tid = threadIdx.x;
  const int j = tid & 15;                       // lane within group == hidden unit
  const int g = tid >> 4;                       // group (batch slot) within block
  const int batch = blockIdx.x * 16 + g;
  const int jo = (j < 5) ? j : 0;               // clamped row for W_lin loads

  // x staging: xs[parity][step-in-chunk][group] as float4 (pad 4th)
  __shared__ float4 xs[2][64][16];
  float4* xsf = &xs[0][0][0];                   // flat: idx = (s&127)*16 + g

  // ---- preload weights into registers, packed by gate-pair, log2e folded
  f32x2 wif[16], wgo[16];                       // {W_i, W_f}[k], {W_g, W_o}[k]
  float wl[16];
#pragma unroll
  for (int k = 0; k < 16; ++k) {
    wif[k] = f32x2{W_hh[(j     ) * 16 + k] * LOG2E,
                   W_hh[(j + 16) * 16 + k] * LOG2E};
    wgo[k] = f32x2{W_hh[(j + 32) * 16 + k] * (2.0f * LOG2E),
                   W_hh[(j + 48) * 16 + k] * LOG2E};
    wl[k]  = W_lin[jo * 16 + k];
  }
  f32x2 xw[3];
#pragma unroll
  for (int i = 0; i < 3; ++i) {
    xw[i] = f32x2{W_ih[(j     ) * 3 + i] * LOG2E,
                  W_ih[(j + 16) * 3 + i] * LOG2E};
  }
  f32x2 xwg[3];
#pragma unroll
  for (int i = 0; i < 3; ++i) {
    xwg[i] = f32x2{W_ih[(j + 32) * 3 + i] * (2.0f * LOG2E),
                   W_ih[(j + 48) * 3 + i] * LOG2E};
  }
  const f32x2 bif = f32x2{(b_ih[j     ] + b_hh[j     ]) * LOG2E,
                          (b_ih[j + 16] + b_hh[j + 16]) * LOG2E};
  const f32x2 bgo = f32x2{(b_ih[j + 32] + b_hh[j + 32]) * (2.0f * LOG2E),
                          (b_ih[j + 48] + b_hh[j + 48]) * LOG2E};
  const float bl = b_lin[jo];

  const float* __restrict__ xb = x + (size_t)batch * (TS * 3);
  float* __restrict__ ob = out + (size_t)batch * (TS * 5) + j;
  const bool storer = (j < 5);

  // ---- staging helpers (intra-wave: group g's lanes handle batch g only)
  // lane j of group g owns steps 4j..4j+3 of each chunk (12 floats, 48 B)
  const float* xc0 = xb + j * 12;               // + chunk*192 floats
  float4 q0, q1, q2;                            // 12 staged floats in flight

  // prologue: stage chunk 0, start loads for chunk 1
  q0 = *(const float4*)(xc0 + 0);
  q1 = *(const float4*)(xc0 + 4);
  q2 = *(const float4*)(xc0 + 8);
  {
    const int wb = j * 4 * 16 + g;              // parity 0 base index
    xsf[wb +  0] = float4{q0.x, q0.y, q0.z, 0.f};
    xsf[wb + 16] = float4{q0.w, q1.x, q1.y, 0.f};
    xsf[wb + 32] = float4{q1.z, q1.w, q2.x, 0.f};
    xsf[wb + 48] = float4{q2.y, q2.z, q2.w, 0.f};
  }
  q0 = *(const float4*)(xc0 + 192 + 0);
  q1 = *(const float4*)(xc0 + 192 + 4);
  q2 = *(const float4*)(xc0 + 192 + 8);

  // prefetch x for steps 0 and 1
  float4 xr[2];
  xr[0] = xsf[0 * 16 + g];
  xr[1] = xsf[1 * 16 + g];

  float h = 0.0f, c = 0.0f;

  auto step = [&](int s, int slot) {
    const float4 xt = xr[slot];
    // issue ds_read for step s+2 into the slot just freed
    xr[slot] = xsf[(((s + 2) & 127) << 4) + g];

    // broadcast h_{t-1} across the 16-lane row (DPP, VALU pipe)
    float hbr[16];
    const int hvi = __float_as_int(h);
    BCAST_ALL();

    // gate pre-activations, two independent pk_fma chains (even/odd k)
    f32x2 aa = bif, ab = f32x2{0.f, 0.f};
    f32x2 ga = bgo, gb = f32x2{0.f, 0.f};
    aa = f32x2{xt.x, xt.x} * xw[0] + aa;
    ab = f32x2{xt.y, xt.y} * xw[1] + ab;
    aa = f32x2{xt.z, xt.z} * xw[2] + aa;
    ga = f32x2{xt.x, xt.x} * xwg[0] + ga;
    gb = f32x2{xt.y, xt.y} * xwg[1] + gb;
    ga = f32x2{xt.z, xt.z} * xwg[2] + ga;
#pragma unroll
    for (int k = 0; k < 16; k += 2) {
      const f32x2 h0 = f32x2{hbr[k], hbr[k]};
      const f32x2 h1 = f32x2{hbr[k + 1], hbr[k + 1]};
      aa = h0 * wif[k] + aa;
      ab = h1 * wif[k + 1] + ab;
      ga = h0 * wgo[k] + ga;
      gb = h1 * wgo[k + 1] + gb;
    }
    const f32x2 zif = aa + ab;
    const f32x2 zgo = ga + gb;

    // output projection W_lin . h_{t-1} -> out[s-1]
    float oa = bl;
#pragma unroll
    for (int k = 0; k < 16; ++k) oa = fmaf(hbr[k], wl[k], oa);
    if (s > 0 && storer) {
      ob[(s - 1) * 5] = fminf(fmaxf(oa, -10.0f), 10.0f);
    }

    // activations: sigmoid(z)=rcp(1+exp2(-z*log2e)); tanh(g)=1-2*rcp(1+exp2(2g*log2e))
    const float ig = __builtin_amdgcn_rcpf(1.0f + __builtin_amdgcn_exp2f(-zif.x));
    const float fg = __builtin_amdgcn_rcpf(1.0f + __builtin_amdgcn_exp2f(-zif.y));
    const float sg = __builtin_amdgcn_rcpf(1.0f + __builtin_amdgcn_exp2f(zgo.x));
    const float og = __builtin_amdgcn_rcpf(1.0f + __builtin_amdgcn_exp2f(-zgo.y));

    const float gg = fmaf(-2.0f, sg, 1.0f);     // tanh(g)
    c = fmaf(fg, c, ig * gg);
    const float tc = fmaf(-2.0f,
        __builtin_amdgcn_rcpf(1.0f + __builtin_amdgcn_exp2f((2.0f * LOG2E) * c)), 1.0f);
    h = og * tc;
  };

  for (int ch = 0; ch < 8; ++ch) {
    const int base = ch * 64;

    // first half of the chunk
#pragma unroll 2
    for (int u = 0; u < 32; ++u) step(base + u, u & 1);

    // mid-chunk: stage chunk ch+1 (regs loaded ~64 steps ago), start ch+2 loads
    if (ch < 7) {
      const int p = (ch + 1) & 1;
      const int wb = p * 1024 + j * 64 + g;     // [p][4j+i][g] flat
      xsf[wb +  0] = float4{q0.x, q0.y, q0.z, 0.f};
      xsf[wb + 16] = float4{q0.w, q1.x, q1.y, 0.f};
      xsf[wb + 32] = float4{q1.z, q1.w, q2.x, 0.f};
      xsf[wb + 48] = float4{q2.y, q2.z, q2.w, 0.f};
    }
    if (ch < 6) {
      const float* xc = xc0 + (ch + 2) * 192;
      q0 = *(const float4*)(xc + 0);
      q1 = *(const float4*)(xc + 4);
      q2 = *(const float4*)(xc + 8);
    }

    // second half of the chunk
#pragma unroll 2
    for (int u = 32; u < 64; ++u) step(base + u, u & 1);
  }

  // final timestep's output (uses h_{S-1})
  {
    float hbr[16];
    const int hvi = __float_as_int(h);
    BCAST_ALL();
    float oa = bl;
#pragma unroll
    for (int k = 0; k < 16; ++k) oa = fmaf(hbr[k], wl[k], oa);
    if (storer) {
      ob[(TS - 1) * 5] = fminf(fmaxf(oa, -10.0f), 10.0f);
    }
  }
}

extern "C" void kernel_launch(void* const* d_in, const int* in_sizes, int n_in,
                              void* d_out, int out_size, void* d_ws, size_t ws_size,
                              hipStream_t stream) {
  const float* x     = (const float*)d_in[0];
  const float* W_ih  = (const float*)d_in[1];
  const float* W_hh  = (const float*)d_in[2];
  const float* b_ih  = (const float*)d_in[3];
  const float* b_hh  = (const float*)d_in[4];
  const float* W_lin = (const float*)d_in[5];
  const float* b_lin = (const float*)d_in[6];
  float* out = (float*)d_out;

  const int B = in_sizes[0] / (TS * 3);   // 4096
  const int grid = B / 16;                // 16 batch elements per 256-thread block
  lstm_enc_kernel<<<grid, 256, 0, stream>>>(x, W_ih, W_hh, b_ih, b_hh, W_lin, b_lin, out);
}

// Round 5
// 213.084 us; speedup vs baseline: 1.2537x; 1.0331x over previous
//
#include <hip/hip_runtime.h>

// SimpleEncoder: LSTM(B=4096, S=512, I=3, H=16) + Linear(16->5) + clip(+-10)
//
// R5 = R4 + amdgpu_waves_per_eu(1,1). R4's VGPR_Count=88 proved the compiler
// was spilling/reloading the ~140-VGPR weight working set every timestep
// (occupancy-driven pressure heuristic). This kernel is grid-limited to
// 1 wave/SIMD (1024 waves on 1024 SIMDs), so the honest budget is 512 VGPRs;
// waves_per_eu(1,1) lets the allocator keep all weights resident.
//
// Layout: 16 lanes/batch, lane j owns unit j (gate rows j/j+16/j+32/j+48).
// h broadcast via DPP row_newbcast (VALU pipe). Gate pairs packed f32x2 ->
// v_pk_fma_f32, dual accumulation chains. x staged through LDS in 64-step
// double-buffered chunks, intra-wave (no barriers); ds_read_b128 prefetched
// 2 steps ahead; global x loads issued a full chunk ahead.

#define TS 512
#define LOG2E 1.44269504088896340736f

typedef float f32x2 __attribute__((ext_vector_type(2)));

// DPP row_newbcast:K — broadcast lane K of each 16-lane row to the whole row.
#define BCAST(K) hbr[K] = __int_as_float( \
    __builtin_amdgcn_update_dpp(0, hvi, 0x150 + (K), 0xf, 0xf, true))
#define BCAST_ALL() \
  BCAST(0); BCAST(1); BCAST(2); BCAST(3); BCAST(4); BCAST(5); BCAST(6); BCAST(7); \
  BCAST(8); BCAST(9); BCAST(10); BCAST(11); BCAST(12); BCAST(13); BCAST(14); BCAST(15)

__global__ __launch_bounds__(256)
__attribute__((amdgpu_waves_per_eu(1, 1)))
void lstm_enc_kernel(const float* __restrict__ x,
                     const float* __restrict__ W_ih,
                     const float* __restrict__ W_hh,
                     const float* __restrict__ b_ih,
                     const float* __restrict__ b_hh,
                     const float* __restrict__ W_lin,
                     const float* __restrict__ b_lin,
                     float* __restrict__ out) {
  const int tid = threadIdx.x;
  const int j = tid & 15;                       // lane within group == hidden unit
  const int g = tid >> 4;                       // group (batch slot) within block
  const int batch = blockIdx.x * 16 + g;
  const int jo = (j < 5) ? j : 0;               // clamped row for W_lin loads

  // x staging: xs[parity][step-in-chunk][group] as float4 (pad 4th)
  __shared__ float4 xs[2][64][16];
  float4* xsf = &xs[0][0][0];                   // flat: idx = (s&127)*16 + g

  // ---- preload weights into registers, packed by gate-pair, log2e folded
  f32x2 wif[16], wgo[16];                       // {W_i, W_f}[k], {W_g, W_o}[k]
  float wl[16];
#pragma unroll
  for (int k = 0; k < 16; ++k) {
    wif[k] = f32x2{W_hh[(j     ) * 16 + k] * LOG2E,
                   W_hh[(j + 16) * 16 + k] * LOG2E};
    wgo[k] = f32x2{W_hh[(j + 32) * 16 + k] * (2.0f * LOG2E),
                   W_hh[(j + 48) * 16 + k] * LOG2E};
    wl[k]  = W_lin[jo * 16 + k];
  }
  f32x2 xw[3], xwg[3];
#pragma unroll
  for (int i = 0; i < 3; ++i) {
    xw[i]  = f32x2{W_ih[(j     ) * 3 + i] * LOG2E,
                   W_ih[(j + 16) * 3 + i] * LOG2E};
    xwg[i] = f32x2{W_ih[(j + 32) * 3 + i] * (2.0f * LOG2E),
                   W_ih[(j + 48) * 3 + i] * LOG2E};
  }
  const f32x2 bif = f32x2{(b_ih[j     ] + b_hh[j     ]) * LOG2E,
                          (b_ih[j + 16] + b_hh[j + 16]) * LOG2E};
  const f32x2 bgo = f32x2{(b_ih[j + 32] + b_hh[j + 32]) * (2.0f * LOG2E),
                          (b_ih[j + 48] + b_hh[j + 48]) * LOG2E};
  const float bl = b_lin[jo];

  const float* __restrict__ xb = x + (size_t)batch * (TS * 3);
  float* __restrict__ ob = out + (size_t)batch * (TS * 5) + j;
  const bool storer = (j < 5);

  // ---- staging (intra-wave: group g's lanes handle batch g only)
  // lane j of group g owns steps 4j..4j+3 of each chunk (12 floats, 48 B)
  const float* xc0 = xb + j * 12;               // + chunk*192 floats
  float4 q0, q1, q2;                            // 12 staged floats in flight

  // prologue: stage chunk 0, start loads for chunk 1
  q0 = *(const float4*)(xc0 + 0);
  q1 = *(const float4*)(xc0 + 4);
  q2 = *(const float4*)(xc0 + 8);
  {
    const int wb = j * 4 * 16 + g;              // parity 0 base index
    xsf[wb +  0] = float4{q0.x, q0.y, q0.z, 0.f};
    xsf[wb + 16] = float4{q0.w, q1.x, q1.y, 0.f};
    xsf[wb + 32] = float4{q1.z, q1.w, q2.x, 0.f};
    xsf[wb + 48] = float4{q2.y, q2.z, q2.w, 0.f};
  }
  q0 = *(const float4*)(xc0 + 192 + 0);
  q1 = *(const float4*)(xc0 + 192 + 4);
  q2 = *(const float4*)(xc0 + 192 + 8);

  // prefetch x for steps 0 and 1
  float4 xr[2];
  xr[0] = xsf[0 * 16 + g];
  xr[1] = xsf[1 * 16 + g];

  float h = 0.0f, c = 0.0f;

  auto step = [&](int s, int slot) {
    const float4 xt = xr[slot];
    // issue ds_read for step s+2 into the slot just freed
    xr[slot] = xsf[(((s + 2) & 127) << 4) + g];

    // broadcast h_{t-1} across the 16-lane row (DPP, VALU pipe)
    float hbr[16];
    const int hvi = __float_as_int(h);
    BCAST_ALL();

    // gate pre-activations, dual pk_fma chains (even/odd k); dual oa chains
    f32x2 aa = bif, ab = f32x2{0.f, 0.f};
    f32x2 ga = bgo, gb = f32x2{0.f, 0.f};
    float oa0 = bl, oa1 = 0.f;
    aa = f32x2{xt.x, xt.x} * xw[0] + aa;
    ab = f32x2{xt.y, xt.y} * xw[1] + ab;
    aa = f32x2{xt.z, xt.z} * xw[2] + aa;
    ga = f32x2{xt.x, xt.x} * xwg[0] + ga;
    gb = f32x2{xt.y, xt.y} * xwg[1] + gb;
    ga = f32x2{xt.z, xt.z} * xwg[2] + ga;
#pragma unroll
    for (int k = 0; k < 16; k += 2) {
      const f32x2 h0 = f32x2{hbr[k], hbr[k]};
      const f32x2 h1 = f32x2{hbr[k + 1], hbr[k + 1]};
      aa = h0 * wif[k] + aa;
      ab = h1 * wif[k + 1] + ab;
      ga = h0 * wgo[k] + ga;
      gb = h1 * wgo[k + 1] + gb;
      oa0 = fmaf(hbr[k], wl[k], oa0);
      oa1 = fmaf(hbr[k + 1], wl[k + 1], oa1);
    }
    const f32x2 zif = aa + ab;
    const f32x2 zgo = ga + gb;

    // output projection W_lin . h_{t-1} -> out[s-1]
    if (s > 0 && storer) {
      const float oa = oa0 + oa1;
      ob[(s - 1) * 5] = fminf(fmaxf(oa, -10.0f), 10.0f);
    }

    // activations: sigmoid(z)=rcp(1+exp2(-z*log2e)); tanh(g)=1-2*rcp(1+exp2(2g*log2e))
    const float ig = __builtin_amdgcn_rcpf(1.0f + __builtin_amdgcn_exp2f(-zif.x));
    const float fg = __builtin_amdgcn_rcpf(1.0f + __builtin_amdgcn_exp2f(-zif.y));
    const float sg = __builtin_amdgcn_rcpf(1.0f + __builtin_amdgcn_exp2f(zgo.x));
    const float og = __builtin_amdgcn_rcpf(1.0f + __builtin_amdgcn_exp2f(-zgo.y));

    const float gg = fmaf(-2.0f, sg, 1.0f);     // tanh(g)
    c = fmaf(fg, c, ig * gg);
    const float tc = fmaf(-2.0f,
        __builtin_amdgcn_rcpf(1.0f + __builtin_amdgcn_exp2f((2.0f * LOG2E) * c)), 1.0f);
    h = og * tc;
  };

  for (int ch = 0; ch < 8; ++ch) {
    const int base = ch * 64;

    // first half of the chunk
#pragma unroll 2
    for (int u = 0; u < 32; ++u) step(base + u, u & 1);

    // mid-chunk: stage chunk ch+1 (regs loaded ~64 steps ago), start ch+2 loads
    if (ch < 7) {
      const int p = (ch + 1) & 1;
      const int wb = p * 1024 + j * 64 + g;     // [p][4j+i][g] flat
      xsf[wb +  0] = float4{q0.x, q0.y, q0.z, 0.f};
      xsf[wb + 16] = float4{q0.w, q1.x, q1.y, 0.f};
      xsf[wb + 32] = float4{q1.z, q1.w, q2.x, 0.f};
      xsf[wb + 48] = float4{q2.y, q2.z, q2.w, 0.f};
    }
    if (ch < 6) {
      const float* xc = xc0 + (ch + 2) * 192;
      q0 = *(const float4*)(xc + 0);
      q1 = *(const float4*)(xc + 4);
      q2 = *(const float4*)(xc + 8);
    }

    // second half of the chunk
#pragma unroll 2
    for (int u = 32; u < 64; ++u) step(base + u, u & 1);
  }

  // final timestep's output (uses h_{S-1})
  {
    float hbr[16];
    const int hvi = __float_as_int(h);
    BCAST_ALL();
    float oa = bl;
#pragma unroll
    for (int k = 0; k < 16; ++k) oa = fmaf(hbr[k], wl[k], oa);
    if (storer) {
      ob[(TS - 1) * 5] = fminf(fmaxf(oa, -10.0f), 10.0f);
    }
  }
}

extern "C" void kernel_launch(void* const* d_in, const int* in_sizes, int n_in,
                              void* d_out, int out_size, void* d_ws, size_t ws_size,
                              hipStream_t stream) {
  const float* x     = (const float*)d_in[0];
  const float* W_ih  = (const float*)d_in[1];
  const float* W_hh  = (const float*)d_in[2];
  const float* b_ih  = (const float*)d_in[3];
  const float* b_hh  = (const float*)d_in[4];
  const float* W_lin = (const float*)d_in[5];
  const float* b_lin = (const float*)d_in[6];
  float* out = (float*)d_out;

  const int B = in_sizes[0] / (TS * 3);   // 4096
  const int grid = B / 16;                // 16 batch elements per 256-thread block
  lstm_enc_kernel<<<grid, 256, 0, stream>>>(x, W_ih, W_hh, b_ih, b_hh, W_lin, b_lin, out);
}